// Round 6
// baseline (2051.240 us; speedup 1.0000x reference)
//
#include <hip/hip_runtime.h>
#include <math.h>

// Problem constants (match reference setup_inputs)
#define BB 8
#define NN 32768          // points per batch (2^15)
#define KK 16             // neighbors
#define NP (BB * NN)      // 262144 center points total
#define LL (NN * KK)      // 524288 positions per batch
#define NSTAT 35          // 7 first moments + 28 second moments (upper tri)
#define NBLKS 1024        // stats blocks: NP threads / 256
#define EPSV 1e-5

// diagnostic repetition factors (push dispatches past the ~335us fills)
#define REP_S 24
#define REP_A 4
#define REP_B 4
#define REP_C 4

// ws layout (bytes)
#define XYZP_OFF 0
#define PART_OFF (NP * 16)
#define FW_OFF   (PART_OFF + NBLKS * NSTAT * 4)

typedef float nfloat4 __attribute__((ext_vector_type(4)));

// ---------------- Kernel 1: transpose xyz [B,3,N] -> [B*N] float4 ----------
__global__ __launch_bounds__(256) void k_transpose(const float* __restrict__ xyz,
                                                   float4* __restrict__ xyzp) {
    int t = blockIdx.x * 256 + threadIdx.x;      // t = b*N + n
    int b = t >> 15;
    int n = t & (NN - 1);
    const float* p = xyz + (size_t)b * 3 * NN + n;
    xyzp[t] = make_float4(p[0], p[NN], p[2 * NN], 0.0f);
}

// ---------------- Kernel 2: moment partials, REPeated for visibility -------
__global__ __launch_bounds__(256) void k_stats_rep(const float4* __restrict__ xyzp,
                                                   const int4* __restrict__ idx4,
                                                   float* __restrict__ partials) {
    __shared__ float red[4][NSTAT];
    int t = blockIdx.x * 256 + threadIdx.x;      // (b,n)
    int b = t >> 15;
    int pbase = b << 15;

    for (int rep = 0; rep < REP_S; ++rep) {
        float4 c = xyzp[t];
        float sd = 0.f, sd2 = 0.f;
        float sg0 = 0.f, sg1 = 0.f, sg2 = 0.f;
        float sdg0 = 0.f, sdg1 = 0.f, sdg2 = 0.f;
        float s00 = 0.f, s01 = 0.f, s02 = 0.f, s11 = 0.f, s12 = 0.f, s22 = 0.f;

        const int4* ib = idx4 + (size_t)t * 4;
#pragma unroll
        for (int q = 0; q < 4; ++q) {
            int4 iv = ib[q];
            int ids[4] = {iv.x, iv.y, iv.z, iv.w};
#pragma unroll
            for (int j = 0; j < 4; ++j) {
                float4 g = xyzp[pbase + ids[j]];
                float r0 = c.x - g.x, r1 = c.y - g.y, r2 = c.z - g.z;
                float d2 = r0 * r0 + r1 * r1 + r2 * r2;
                float d  = sqrtf(d2);
                sd += d;  sd2 += d2;
                sg0 += g.x; sg1 += g.y; sg2 += g.z;
                sdg0 += d * g.x; sdg1 += d * g.y; sdg2 += d * g.z;
                s00 += g.x * g.x; s01 += g.x * g.y; s02 += g.x * g.z;
                s11 += g.y * g.y; s12 += g.y * g.z; s22 += g.z * g.z;
            }
        }

        float v[NSTAT];
        v[0] = sd;  v[1] = 16.f * c.x; v[2] = 16.f * c.y; v[3] = 16.f * c.z;
        v[4] = sg0; v[5] = sg1; v[6] = sg2;
        v[7]  = sd2;
        v[8]  = c.x * sd; v[9]  = c.y * sd; v[10] = c.z * sd;
        v[11] = sdg0; v[12] = sdg1; v[13] = sdg2;
        v[14] = 16.f * c.x * c.x; v[15] = 16.f * c.x * c.y; v[16] = 16.f * c.x * c.z;
        v[17] = c.x * sg0; v[18] = c.x * sg1; v[19] = c.x * sg2;
        v[20] = 16.f * c.y * c.y; v[21] = 16.f * c.y * c.z;
        v[22] = c.y * sg0; v[23] = c.y * sg1; v[24] = c.y * sg2;
        v[25] = 16.f * c.z * c.z;
        v[26] = c.z * sg0; v[27] = c.z * sg1; v[28] = c.z * sg2;
        v[29] = s00; v[30] = s01; v[31] = s02;
        v[32] = s11; v[33] = s12;
        v[34] = s22;

#pragma unroll
        for (int j = 0; j < NSTAT; ++j) {
            float x = v[j];
#pragma unroll
            for (int m = 32; m >= 1; m >>= 1) x += __shfl_xor(x, m, 64);
            v[j] = x;
        }

        int wave = threadIdx.x >> 6;
        int lane = threadIdx.x & 63;
        if (lane == 0) {
#pragma unroll
            for (int j = 0; j < NSTAT; ++j) red[wave][j] = v[j];
        }
        __syncthreads();
        if (threadIdx.x < NSTAT) {
            int j = threadIdx.x;
            partials[(size_t)blockIdx.x * NSTAT + j] =
                red[0][j] + red[1][j] + red[2][j] + red[3][j];
        }
        __syncthreads();
        asm volatile("" ::: "memory");
    }
}

// ---------------- Kernel 3: finalize stats, fold BN into conv --------------
__global__ void k_finalize(const float* __restrict__ partials,
                           const float* __restrict__ W,
                           const float* __restrict__ bias,
                           const float* __restrict__ gamma,
                           const float* __restrict__ beta,
                           float* __restrict__ fw) {
    __shared__ double part[8][NSTAT];
    __shared__ double st[NSTAT];
    int j  = threadIdx.x;   // 0..34
    int cy = threadIdx.y;   // 0..7
    double s = 0.0;
    for (int i = cy * 128; i < (cy + 1) * 128; ++i)
        s += (double)partials[(size_t)i * NSTAT + j];
    part[cy][j] = s;
    __syncthreads();
    if (cy == 0) {
        double tot = 0.0;
        for (int y = 0; y < 8; ++y) tot += part[y][j];
        st[j] = tot;
    }
    __syncthreads();

    int tid = cy * 35 + j;
    if (tid < 32) {
        int o = tid;
        double M[7];
        M[0] = (double)W[o * 10 + 0];
        for (int x = 0; x < 3; ++x) {
            M[1 + x] = (double)W[o * 10 + 1 + x] + (double)W[o * 10 + 4 + x];
            M[4 + x] = (double)W[o * 10 + 7 + x] - (double)W[o * 10 + 1 + x];
        }
        const double inv = 1.0 / ((double)BB * (double)LL);
        double mf[7];
        for (int i = 0; i < 7; ++i) mf[i] = st[i] * inv;
        double mh = (double)bias[o];
        for (int i = 0; i < 7; ++i) mh += M[i] * mf[i];
        double var = 0.0;
        for (int i = 0; i < 7; ++i)
            for (int k = 0; k < 7; ++k) {
                int a = i < k ? i : k;
                int b2 = i < k ? k : i;
                int u = 7 + 7 * a - (a * (a - 1)) / 2 + (b2 - a);
                double cov = st[u] * inv - mf[i] * mf[k];
                var += M[i] * M[k] * cov;
            }
        double sc = (double)gamma[o] / sqrt(var + EPSV);
        for (int x = 0; x < 7; ++x) fw[o * 8 + x] = (float)(M[x] * sc);
        fw[o * 8 + 7] = (float)(((double)bias[o] - mh) * sc + (double)beta[o]);
    }
}

// ------- Kernel B: STORE-ONLY null test (zeros, exact output addressing) ---
__global__ __launch_bounds__(256) void k_apply_B(float* __restrict__ out) {
    int t  = blockIdx.x * 256 + threadIdx.x;   // [0, NP*4)
    int ng = t >> 2;
    int b  = ng >> 15;
    int nb = ng & (NN - 1);
    int kq = t & 3;
    float* op = out + (size_t)b * 32 * LL + (size_t)nb * 16 + kq * 4;
    float4 z = make_float4(0.f, 0.f, 0.f, 0.f);
    for (int rep = 0; rep < REP_B; ++rep) {
#pragma unroll 8
        for (int o = 0; o < 32; ++o)
            *(float4*)(op + (size_t)o * LL) = z;
        asm volatile("" ::: "memory");
    }
}

// ------- Kernel C: full apply with NONTEMPORAL stores ----------------------
__global__ __launch_bounds__(256) void k_apply_C(const float4* __restrict__ xyzp,
                                                 const int4* __restrict__ idx4,
                                                 const float* __restrict__ fw,
                                                 float* __restrict__ out) {
    int t  = blockIdx.x * 256 + threadIdx.x;
    int ng = t >> 2;
    int b  = ng >> 15;
    int nb = ng & (NN - 1);
    int kq = t & 3;
    int pbase = b << 15;
    float* op = out + (size_t)b * 32 * LL + (size_t)nb * 16 + kq * 4;
    const float4* fw4 = (const float4*)fw;

    for (int rep = 0; rep < REP_C; ++rep) {
        float4 c  = xyzp[ng];
        int4   iv = idx4[t];
        int ids[4] = {iv.x, iv.y, iv.z, iv.w};
        float d[4], gx[4], gy[4], gz[4];
#pragma unroll
        for (int j = 0; j < 4; ++j) {
            float4 g = xyzp[pbase + ids[j]];
            float r0 = c.x - g.x, r1 = c.y - g.y, r2 = c.z - g.z;
            d[j]  = sqrtf(r0 * r0 + r1 * r1 + r2 * r2);
            gx[j] = g.x; gy[j] = g.y; gz[j] = g.z;
        }
#pragma unroll 8
        for (int o = 0; o < 32; ++o) {
            float4 wA = fw4[o * 2];
            float4 wB = fw4[o * 2 + 1];
            float hc = wB.w + wA.y * c.x + wA.z * c.y + wA.w * c.z;
            float h0 = hc + wA.x * d[0] + wB.x * gx[0] + wB.y * gy[0] + wB.z * gz[0];
            float h1 = hc + wA.x * d[1] + wB.x * gx[1] + wB.y * gy[1] + wB.z * gz[1];
            float h2 = hc + wA.x * d[2] + wB.x * gx[2] + wB.y * gy[2] + wB.z * gz[2];
            float h3 = hc + wA.x * d[3] + wB.x * gx[3] + wB.y * gy[3] + wB.z * gz[3];
            nfloat4 r = {fmaxf(h0, 0.01f * h0), fmaxf(h1, 0.01f * h1),
                         fmaxf(h2, 0.01f * h2), fmaxf(h3, 0.01f * h3)};
            __builtin_nontemporal_store(r, (nfloat4*)(op + (size_t)o * LL));
        }
        asm volatile("" ::: "memory");
    }
}

// ------- Kernel A: R1-style register-flow apply, normal stores, runs LAST --
__global__ __launch_bounds__(256) void k_apply_A(const float4* __restrict__ xyzp,
                                                 const int4* __restrict__ idx4,
                                                 const float* __restrict__ fw,
                                                 float* __restrict__ out) {
    int t  = blockIdx.x * 256 + threadIdx.x;
    int ng = t >> 2;
    int b  = ng >> 15;
    int nb = ng & (NN - 1);
    int kq = t & 3;
    int pbase = b << 15;
    float* op = out + (size_t)b * 32 * LL + (size_t)nb * 16 + kq * 4;
    const float4* fw4 = (const float4*)fw;

    for (int rep = 0; rep < REP_A; ++rep) {
        float4 c  = xyzp[ng];
        int4   iv = idx4[t];
        int ids[4] = {iv.x, iv.y, iv.z, iv.w};
        float d[4], gx[4], gy[4], gz[4];
#pragma unroll
        for (int j = 0; j < 4; ++j) {
            float4 g = xyzp[pbase + ids[j]];
            float r0 = c.x - g.x, r1 = c.y - g.y, r2 = c.z - g.z;
            d[j]  = sqrtf(r0 * r0 + r1 * r1 + r2 * r2);
            gx[j] = g.x; gy[j] = g.y; gz[j] = g.z;
        }
#pragma unroll 8
        for (int o = 0; o < 32; ++o) {
            float4 wA = fw4[o * 2];
            float4 wB = fw4[o * 2 + 1];
            float hc = wB.w + wA.y * c.x + wA.z * c.y + wA.w * c.z;
            float4 r;
            float h0 = hc + wA.x * d[0] + wB.x * gx[0] + wB.y * gy[0] + wB.z * gz[0];
            float h1 = hc + wA.x * d[1] + wB.x * gx[1] + wB.y * gy[1] + wB.z * gz[1];
            float h2 = hc + wA.x * d[2] + wB.x * gx[2] + wB.y * gy[2] + wB.z * gz[2];
            float h3 = hc + wA.x * d[3] + wB.x * gx[3] + wB.y * gy[3] + wB.z * gz[3];
            r.x = fmaxf(h0, 0.01f * h0);
            r.y = fmaxf(h1, 0.01f * h1);
            r.z = fmaxf(h2, 0.01f * h2);
            r.w = fmaxf(h3, 0.01f * h3);
            *(float4*)(op + (size_t)o * LL) = r;
        }
        asm volatile("" ::: "memory");
    }
}

extern "C" void kernel_launch(void* const* d_in, const int* in_sizes, int n_in,
                              void* d_out, int out_size, void* d_ws, size_t ws_size,
                              hipStream_t stream) {
    const float* xyz   = (const float*)d_in[0];
    const int*   nidx  = (const int*)d_in[1];
    const float* W     = (const float*)d_in[2];
    const float* bias  = (const float*)d_in[3];
    const float* gamma = (const float*)d_in[4];
    const float* beta  = (const float*)d_in[5];
    float*       out   = (float*)d_out;

    char* ws = (char*)d_ws;
    float4* xyzp    = (float4*)(ws + XYZP_OFF);
    float*  partial = (float*)(ws + PART_OFF);
    float*  fw      = (float*)(ws + FW_OFF);
    const int4* idx4 = (const int4*)nidx;

    k_transpose<<<NP / 256, 256, 0, stream>>>(xyz, xyzp);
    k_stats_rep<<<NBLKS, 256, 0, stream>>>(xyzp, idx4, partial);
    k_finalize<<<1, dim3(35, 8), 0, stream>>>(partial, W, bias, gamma, beta, fw);
    // Diagnostic A/B/C: B = store-only zeros, C = NT-store full apply,
    // A = normal-store full apply (LAST => final output correct).
    k_apply_B<<<(NP * 4) / 256, 256, 0, stream>>>(out);
    k_apply_C<<<(NP * 4) / 256, 256, 0, stream>>>(xyzp, idx4, fw, out);
    k_apply_A<<<(NP * 4) / 256, 256, 0, stream>>>(xyzp, idx4, fw, out);
}

// Round 7
// 1083.462 us; speedup vs baseline: 1.8932x; 1.8932x over previous
//
#include <hip/hip_runtime.h>
#include <math.h>

// Problem constants (match reference setup_inputs)
#define BB 8
#define NN 32768          // points per batch (2^15)
#define KK 16             // neighbors
#define NP (BB * NN)      // 262144 center points total
#define LL (NN * KK)      // 524288 positions per batch
#define NSTAT 35          // 7 first + 28 second moments (upper tri)
#define NBLKS 1024        // stats blocks: NP threads / 256
#define EPSV 1e-5

#define REP_B 6           // diagnostic reps for store-only kernel (visible in top-5)

#define CHP 2048          // positions per apply chunk
#define CHQ 512           // quads per chunk
#define NCHB 256          // chunks per batch

// ws layout (bytes)
#define XYZP_OFF 0
#define PART_OFF (NP * 16)
#define FW_OFF   (PART_OFF + NBLKS * NSTAT * 4)

typedef float nfloat4 __attribute__((ext_vector_type(4)));

// ---------------- Kernel 1: transpose xyz [B,3,N] -> [B*N] float4 ----------
__global__ __launch_bounds__(256) void k_transpose(const float* __restrict__ xyz,
                                                   float4* __restrict__ xyzp) {
    int t = blockIdx.x * 256 + threadIdx.x;      // t = b*N + n
    int b = t >> 15;
    int n = t & (NN - 1);
    const float* p = xyz + (size_t)b * 3 * NN + n;
    xyzp[t] = make_float4(p[0], p[NN], p[2 * NN], 0.0f);
}

// ---------------- Kernel 2: moment partials (R1 form, 1 point/thread) ------
__global__ __launch_bounds__(256) void k_stats(const float4* __restrict__ xyzp,
                                               const int4* __restrict__ idx4,
                                               float* __restrict__ partials) {
    int t = blockIdx.x * 256 + threadIdx.x;      // (b,n)
    int b = t >> 15;
    int pbase = b << 15;
    float4 c = xyzp[t];

    float sd = 0.f, sd2 = 0.f;
    float sg0 = 0.f, sg1 = 0.f, sg2 = 0.f;
    float sdg0 = 0.f, sdg1 = 0.f, sdg2 = 0.f;
    float s00 = 0.f, s01 = 0.f, s02 = 0.f, s11 = 0.f, s12 = 0.f, s22 = 0.f;

    const int4* ib = idx4 + (size_t)t * 4;
#pragma unroll
    for (int q = 0; q < 4; ++q) {
        int4 iv = ib[q];
        int ids[4] = {iv.x, iv.y, iv.z, iv.w};
#pragma unroll
        for (int j = 0; j < 4; ++j) {
            float4 g = xyzp[pbase + ids[j]];
            float r0 = c.x - g.x, r1 = c.y - g.y, r2 = c.z - g.z;
            float d2 = r0 * r0 + r1 * r1 + r2 * r2;
            float d  = sqrtf(d2);
            sd += d;  sd2 += d2;
            sg0 += g.x; sg1 += g.y; sg2 += g.z;
            sdg0 += d * g.x; sdg1 += d * g.y; sdg2 += d * g.z;
            s00 += g.x * g.x; s01 += g.x * g.y; s02 += g.x * g.z;
            s11 += g.y * g.y; s12 += g.y * g.z; s22 += g.z * g.z;
        }
    }

    float v[NSTAT];
    v[0] = sd;  v[1] = 16.f * c.x; v[2] = 16.f * c.y; v[3] = 16.f * c.z;
    v[4] = sg0; v[5] = sg1; v[6] = sg2;
    v[7]  = sd2;
    v[8]  = c.x * sd; v[9]  = c.y * sd; v[10] = c.z * sd;
    v[11] = sdg0; v[12] = sdg1; v[13] = sdg2;
    v[14] = 16.f * c.x * c.x; v[15] = 16.f * c.x * c.y; v[16] = 16.f * c.x * c.z;
    v[17] = c.x * sg0; v[18] = c.x * sg1; v[19] = c.x * sg2;
    v[20] = 16.f * c.y * c.y; v[21] = 16.f * c.y * c.z;
    v[22] = c.y * sg0; v[23] = c.y * sg1; v[24] = c.y * sg2;
    v[25] = 16.f * c.z * c.z;
    v[26] = c.z * sg0; v[27] = c.z * sg1; v[28] = c.z * sg2;
    v[29] = s00; v[30] = s01; v[31] = s02;
    v[32] = s11; v[33] = s12;
    v[34] = s22;

#pragma unroll
    for (int j = 0; j < NSTAT; ++j) {
        float x = v[j];
#pragma unroll
        for (int m = 32; m >= 1; m >>= 1) x += __shfl_xor(x, m, 64);
        v[j] = x;
    }

    __shared__ float red[4][NSTAT];
    int wave = threadIdx.x >> 6;
    int lane = threadIdx.x & 63;
    if (lane == 0) {
#pragma unroll
        for (int j = 0; j < NSTAT; ++j) red[wave][j] = v[j];
    }
    __syncthreads();
    if (threadIdx.x < NSTAT) {
        int j = threadIdx.x;
        partials[(size_t)blockIdx.x * NSTAT + j] =
            red[0][j] + red[1][j] + red[2][j] + red[3][j];
    }
}

// ---------------- Kernel 3: finalize stats, fold BN into conv --------------
__global__ void k_finalize(const float* __restrict__ partials,
                           const float* __restrict__ W,
                           const float* __restrict__ bias,
                           const float* __restrict__ gamma,
                           const float* __restrict__ beta,
                           float* __restrict__ fw) {
    __shared__ double part[8][NSTAT];
    __shared__ double st[NSTAT];
    int j  = threadIdx.x;   // 0..34
    int cy = threadIdx.y;   // 0..7
    double s = 0.0;
    for (int i = cy * 128; i < (cy + 1) * 128; ++i)
        s += (double)partials[(size_t)i * NSTAT + j];
    part[cy][j] = s;
    __syncthreads();
    if (cy == 0) {
        double tot = 0.0;
        for (int y = 0; y < 8; ++y) tot += part[y][j];
        st[j] = tot;
    }
    __syncthreads();

    int tid = cy * 35 + j;
    if (tid < 32) {
        int o = tid;
        double M[7];
        M[0] = (double)W[o * 10 + 0];
        for (int x = 0; x < 3; ++x) {
            M[1 + x] = (double)W[o * 10 + 1 + x] + (double)W[o * 10 + 4 + x];
            M[4 + x] = (double)W[o * 10 + 7 + x] - (double)W[o * 10 + 1 + x];
        }
        const double inv = 1.0 / ((double)BB * (double)LL);
        double mf[7];
        for (int i = 0; i < 7; ++i) mf[i] = st[i] * inv;
        double mh = (double)bias[o];
        for (int i = 0; i < 7; ++i) mh += M[i] * mf[i];
        double var = 0.0;
        for (int i = 0; i < 7; ++i)
            for (int k = 0; k < 7; ++k) {
                int a = i < k ? i : k;
                int b2 = i < k ? k : i;
                int u = 7 + 7 * a - (a * (a - 1)) / 2 + (b2 - a);
                double cov = st[u] * inv - mf[i] * mf[k];
                var += M[i] * M[k] * cov;
            }
        double sc = (double)gamma[o] / sqrt(var + EPSV);
        for (int x = 0; x < 7; ++x) fw[o * 8 + x] = (float)(M[x] * sc);
        fw[o * 8 + 7] = (float)(((double)bias[o] - mh) * sc + (double)beta[o]);
    }
}

// ------- Kernel B: STORE-ONLY diagnostic, OLD interleaved pattern, REP 6 ---
// Measures the pure-store ceiling of the 32-stream 2-MiB-strided pattern.
// Writes zeros; runs BEFORE the real apply so the final output is correct.
__global__ __launch_bounds__(256) void k_apply_B(float* __restrict__ out) {
    int t  = blockIdx.x * 256 + threadIdx.x;   // [0, NP*4)
    int ng = t >> 2;
    int b  = ng >> 15;
    int nb = ng & (NN - 1);
    int kq = t & 3;
    float* op = out + (size_t)b * 32 * LL + (size_t)nb * 16 + kq * 4;
    float4 z = make_float4(0.f, 0.f, 0.f, 0.f);
    for (int rep = 0; rep < REP_B; ++rep) {
#pragma unroll 8
        for (int o = 0; o < 32; ++o)
            *(float4*)(op + (size_t)o * LL) = z;
        asm volatile("" ::: "memory");
    }
}

// ------- Kernel 4 (real): LDS-staged apply, long contiguous NT writes ------
// Block = (b, ch): 2048 positions. Phase A: gather once -> 32 KB SoA LDS
// (4 blocks/CU). Phase B: o-loop (rotated per block), per o an 8-KB
// CONTIGUOUS nontemporal write run.
__global__ __launch_bounds__(256) void k_apply_v2(const float4* __restrict__ xyzp,
                                                  const int4* __restrict__ idx4,
                                                  const float* __restrict__ fw,
                                                  float* __restrict__ out) {
    __shared__ float sdl[CHP], sgx[CHP], sgy[CHP], sgz[CHP];   // 32 KiB
    int bid = blockIdx.x;        // 0..2047
    int b   = bid >> 8;
    int ch  = bid & (NCHB - 1);
    int tid = threadIdx.x;
    int pbase = b << 15;
    size_t qglob = (size_t)bid * CHQ;

    // Phase A: gather 2048 positions -> SoA LDS
#pragma unroll
    for (int it = 0; it < 2; ++it) {
        int q  = it * 256 + tid;                 // quad in chunk [0,512)
        int qb = ch * CHQ + q;                   // quad within batch
        int4 iv = idx4[qglob + q];
        float4 c = xyzp[pbase + (qb >> 2)];
        int ids[4] = {iv.x, iv.y, iv.z, iv.w};
        float dv[4], gxv[4], gyv[4], gzv[4];
#pragma unroll
        for (int j = 0; j < 4; ++j) {
            float4 g = xyzp[pbase + ids[j]];
            float r0 = c.x - g.x, r1 = c.y - g.y, r2 = c.z - g.z;
            dv[j]  = sqrtf(r0 * r0 + r1 * r1 + r2 * r2);
            gxv[j] = g.x; gyv[j] = g.y; gzv[j] = g.z;
        }
        *(float4*)&sdl[q * 4] = make_float4(dv[0], dv[1], dv[2], dv[3]);
        *(float4*)&sgx[q * 4] = make_float4(gxv[0], gxv[1], gxv[2], gxv[3]);
        *(float4*)&sgy[q * 4] = make_float4(gyv[0], gyv[1], gyv[2], gyv[3]);
        *(float4*)&sgz[q * 4] = make_float4(gzv[0], gzv[1], gzv[2], gzv[3]);
    }
    __syncthreads();

    // centers for this thread's two quad slots
    float4 c0 = xyzp[pbase + ((ch * CHQ + tid) >> 2)];
    float4 c1 = xyzp[pbase + ((ch * CHQ + 256 + tid) >> 2)];

    const float4* fw4 = (const float4*)fw;
    float* ob = out + (size_t)b * 32 * LL + (size_t)ch * CHP;
#pragma unroll 4
    for (int oi = 0; oi < 32; ++oi) {
        int o = (oi + bid) & 31;                 // per-block slab rotation
        float4 wA = fw4[o * 2];                  // {A, U0, U1, U2}
        float4 wB = fw4[o * 2 + 1];              // {V0, V1, V2, Fb}
        float* oo = ob + (size_t)o * LL;
#pragma unroll
        for (int it2 = 0; it2 < 2; ++it2) {
            int q2 = it2 * 256 + tid;
            float4 c = it2 ? c1 : c0;
            float hc = wB.w + wA.y * c.x + wA.z * c.y + wA.w * c.z;
            float4 d4 = *(const float4*)&sdl[q2 * 4];
            float4 x4 = *(const float4*)&sgx[q2 * 4];
            float4 y4 = *(const float4*)&sgy[q2 * 4];
            float4 z4 = *(const float4*)&sgz[q2 * 4];
            float h0 = hc + wA.x * d4.x + wB.x * x4.x + wB.y * y4.x + wB.z * z4.x;
            float h1 = hc + wA.x * d4.y + wB.x * x4.y + wB.y * y4.y + wB.z * z4.y;
            float h2 = hc + wA.x * d4.z + wB.x * x4.z + wB.y * y4.z + wB.z * z4.z;
            float h3 = hc + wA.x * d4.w + wB.x * x4.w + wB.y * y4.w + wB.z * z4.w;
            nfloat4 r = {fmaxf(h0, 0.01f * h0), fmaxf(h1, 0.01f * h1),
                         fmaxf(h2, 0.01f * h2), fmaxf(h3, 0.01f * h3)};
            __builtin_nontemporal_store(r, (nfloat4*)(oo + q2 * 4));
        }
    }
}

extern "C" void kernel_launch(void* const* d_in, const int* in_sizes, int n_in,
                              void* d_out, int out_size, void* d_ws, size_t ws_size,
                              hipStream_t stream) {
    const float* xyz   = (const float*)d_in[0];
    const int*   nidx  = (const int*)d_in[1];
    const float* W     = (const float*)d_in[2];
    const float* bias  = (const float*)d_in[3];
    const float* gamma = (const float*)d_in[4];
    const float* beta  = (const float*)d_in[5];
    float*       out   = (float*)d_out;

    char* ws = (char*)d_ws;
    float4* xyzp    = (float4*)(ws + XYZP_OFF);
    float*  partial = (float*)(ws + PART_OFF);
    float*  fw      = (float*)(ws + FW_OFF);
    const int4* idx4 = (const int4*)nidx;

    k_transpose<<<NP / 256, 256, 0, stream>>>(xyz, xyzp);
    k_stats<<<NBLKS, 256, 0, stream>>>(xyzp, idx4, partial);
    k_finalize<<<1, dim3(35, 8), 0, stream>>>(partial, W, bias, gamma, beta, fw);
    // Diagnostic: old-pattern store-only ceiling (writes zeros, overwritten next)
    k_apply_B<<<(NP * 4) / 256, 256, 0, stream>>>(out);
    // Real apply: long contiguous NT writes
    k_apply_v2<<<BB * NCHB, 256, 0, stream>>>(xyzp, idx4, fw, out);
}

// Round 8
// 149.124 us; speedup vs baseline: 13.7553x; 7.2655x over previous
//
#include <hip/hip_runtime.h>
#include <math.h>

// Problem constants (match reference setup_inputs)
#define BB 8
#define NN 32768          // points per batch (2^15)
#define KK 16             // neighbors
#define NP (BB * NN)      // 262144 center points total
#define LL (NN * KK)      // 524288 positions per batch
#define NSTAT 35          // 7 first + 28 second moments (upper tri)
#define NBLKS 1024        // stats blocks: NP threads / 256
#define EPSV 1e-5

#define CHP 2048          // positions per apply chunk
#define CHQ 512           // quads per chunk
#define NCHB 256          // chunks per batch

// ws layout (bytes)
#define XYZP_OFF 0
#define PART_OFF (NP * 16)
#define FW_OFF   (PART_OFF + NBLKS * NSTAT * 4)

typedef float nfloat4 __attribute__((ext_vector_type(4)));

// ---------------- Kernel 1: transpose xyz [B,3,N] -> [B*N] float4 ----------
__global__ __launch_bounds__(256) void k_transpose(const float* __restrict__ xyz,
                                                   float4* __restrict__ xyzp) {
    int t = blockIdx.x * 256 + threadIdx.x;      // t = b*N + n
    int b = t >> 15;
    int n = t & (NN - 1);
    const float* p = xyz + (size_t)b * 3 * NN + n;
    xyzp[t] = make_float4(p[0], p[NN], p[2 * NN], 0.0f);
}

// ---------------- Kernel 2: moment partials (1 point/thread) ---------------
// Features f = (d, c0,c1,c2, g0,g1,g2). Accumulate S1[7], S2 upper-tri[28].
__global__ __launch_bounds__(256) void k_stats(const float4* __restrict__ xyzp,
                                               const int4* __restrict__ idx4,
                                               float* __restrict__ partials) {
    int t = blockIdx.x * 256 + threadIdx.x;      // (b,n)
    int b = t >> 15;
    int pbase = b << 15;
    float4 c = xyzp[t];

    float sd = 0.f, sd2 = 0.f;
    float sg0 = 0.f, sg1 = 0.f, sg2 = 0.f;
    float sdg0 = 0.f, sdg1 = 0.f, sdg2 = 0.f;
    float s00 = 0.f, s01 = 0.f, s02 = 0.f, s11 = 0.f, s12 = 0.f, s22 = 0.f;

    const int4* ib = idx4 + (size_t)t * 4;
#pragma unroll
    for (int q = 0; q < 4; ++q) {
        int4 iv = ib[q];
        int ids[4] = {iv.x, iv.y, iv.z, iv.w};
#pragma unroll
        for (int j = 0; j < 4; ++j) {
            float4 g = xyzp[pbase + ids[j]];
            float r0 = c.x - g.x, r1 = c.y - g.y, r2 = c.z - g.z;
            float d2 = r0 * r0 + r1 * r1 + r2 * r2;
            float d  = sqrtf(d2);
            sd += d;  sd2 += d2;
            sg0 += g.x; sg1 += g.y; sg2 += g.z;
            sdg0 += d * g.x; sdg1 += d * g.y; sdg2 += d * g.z;
            s00 += g.x * g.x; s01 += g.x * g.y; s02 += g.x * g.z;
            s11 += g.y * g.y; s12 += g.y * g.z; s22 += g.z * g.z;
        }
    }

    float v[NSTAT];
    v[0] = sd;  v[1] = 16.f * c.x; v[2] = 16.f * c.y; v[3] = 16.f * c.z;
    v[4] = sg0; v[5] = sg1; v[6] = sg2;
    v[7]  = sd2;
    v[8]  = c.x * sd; v[9]  = c.y * sd; v[10] = c.z * sd;
    v[11] = sdg0; v[12] = sdg1; v[13] = sdg2;
    v[14] = 16.f * c.x * c.x; v[15] = 16.f * c.x * c.y; v[16] = 16.f * c.x * c.z;
    v[17] = c.x * sg0; v[18] = c.x * sg1; v[19] = c.x * sg2;
    v[20] = 16.f * c.y * c.y; v[21] = 16.f * c.y * c.z;
    v[22] = c.y * sg0; v[23] = c.y * sg1; v[24] = c.y * sg2;
    v[25] = 16.f * c.z * c.z;
    v[26] = c.z * sg0; v[27] = c.z * sg1; v[28] = c.z * sg2;
    v[29] = s00; v[30] = s01; v[31] = s02;
    v[32] = s11; v[33] = s12;
    v[34] = s22;

#pragma unroll
    for (int j = 0; j < NSTAT; ++j) {
        float x = v[j];
#pragma unroll
        for (int m = 32; m >= 1; m >>= 1) x += __shfl_xor(x, m, 64);
        v[j] = x;
    }

    __shared__ float red[4][NSTAT];
    int wave = threadIdx.x >> 6;
    int lane = threadIdx.x & 63;
    if (lane == 0) {
#pragma unroll
        for (int j = 0; j < NSTAT; ++j) red[wave][j] = v[j];
    }
    __syncthreads();
    if (threadIdx.x < NSTAT) {
        int j = threadIdx.x;
        partials[(size_t)blockIdx.x * NSTAT + j] =
            red[0][j] + red[1][j] + red[2][j] + red[3][j];
    }
}

// ---------------- Kernel 3: finalize stats, fold BN into conv --------------
__global__ void k_finalize(const float* __restrict__ partials,
                           const float* __restrict__ W,
                           const float* __restrict__ bias,
                           const float* __restrict__ gamma,
                           const float* __restrict__ beta,
                           float* __restrict__ fw) {
    __shared__ double part[8][NSTAT];
    __shared__ double st[NSTAT];
    int j  = threadIdx.x;   // 0..34
    int cy = threadIdx.y;   // 0..7
    double s = 0.0;
    for (int i = cy * 128; i < (cy + 1) * 128; ++i)
        s += (double)partials[(size_t)i * NSTAT + j];
    part[cy][j] = s;
    __syncthreads();
    if (cy == 0) {
        double tot = 0.0;
        for (int y = 0; y < 8; ++y) tot += part[y][j];
        st[j] = tot;
    }
    __syncthreads();

    int tid = cy * 35 + j;
    if (tid < 32) {
        int o = tid;
        double M[7];
        M[0] = (double)W[o * 10 + 0];
        for (int x = 0; x < 3; ++x) {
            M[1 + x] = (double)W[o * 10 + 1 + x] + (double)W[o * 10 + 4 + x];
            M[4 + x] = (double)W[o * 10 + 7 + x] - (double)W[o * 10 + 1 + x];
        }
        const double inv = 1.0 / ((double)BB * (double)LL);
        double mf[7];
        for (int i = 0; i < 7; ++i) mf[i] = st[i] * inv;
        double mh = (double)bias[o];
        for (int i = 0; i < 7; ++i) mh += M[i] * mf[i];
        double var = 0.0;
        for (int i = 0; i < 7; ++i)
            for (int k = 0; k < 7; ++k) {
                int a = i < k ? i : k;
                int b2 = i < k ? k : i;
                int u = 7 + 7 * a - (a * (a - 1)) / 2 + (b2 - a);
                double cov = st[u] * inv - mf[i] * mf[k];
                var += M[i] * M[k] * cov;
            }
        double sc = (double)gamma[o] / sqrt(var + EPSV);
        for (int x = 0; x < 7; ++x) fw[o * 8 + x] = (float)(M[x] * sc);
        fw[o * 8 + 7] = (float)(((double)bias[o] - mh) * sc + (double)beta[o]);
    }
}

// ---------------- Kernel 4: LDS-staged apply, long contiguous NT writes ----
// Block = (b, ch): 2048 positions. Phase A: gather once -> 32 KB SoA LDS
// (4 blocks/CU). Phase B: o-loop (rotated per block), per o an 8-KB
// CONTIGUOUS nontemporal write run. Measured ~90 us (R7): interleaved
// 2-MiB-strided stores cap at 3.3 TB/s; this pattern reaches ~6 TB/s.
__global__ __launch_bounds__(256) void k_apply_v2(const float4* __restrict__ xyzp,
                                                  const int4* __restrict__ idx4,
                                                  const float* __restrict__ fw,
                                                  float* __restrict__ out) {
    __shared__ float sdl[CHP], sgx[CHP], sgy[CHP], sgz[CHP];   // 32 KiB
    int bid = blockIdx.x;        // 0..2047
    int b   = bid >> 8;
    int ch  = bid & (NCHB - 1);
    int tid = threadIdx.x;
    int pbase = b << 15;
    size_t qglob = (size_t)bid * CHQ;

    // Phase A: gather 2048 positions -> SoA LDS
#pragma unroll
    for (int it = 0; it < 2; ++it) {
        int q  = it * 256 + tid;                 // quad in chunk [0,512)
        int qb = ch * CHQ + q;                   // quad within batch
        int4 iv = idx4[qglob + q];
        float4 c = xyzp[pbase + (qb >> 2)];
        int ids[4] = {iv.x, iv.y, iv.z, iv.w};
        float dv[4], gxv[4], gyv[4], gzv[4];
#pragma unroll
        for (int j = 0; j < 4; ++j) {
            float4 g = xyzp[pbase + ids[j]];
            float r0 = c.x - g.x, r1 = c.y - g.y, r2 = c.z - g.z;
            dv[j]  = sqrtf(r0 * r0 + r1 * r1 + r2 * r2);
            gxv[j] = g.x; gyv[j] = g.y; gzv[j] = g.z;
        }
        *(float4*)&sdl[q * 4] = make_float4(dv[0], dv[1], dv[2], dv[3]);
        *(float4*)&sgx[q * 4] = make_float4(gxv[0], gxv[1], gxv[2], gxv[3]);
        *(float4*)&sgy[q * 4] = make_float4(gyv[0], gyv[1], gyv[2], gyv[3]);
        *(float4*)&sgz[q * 4] = make_float4(gzv[0], gzv[1], gzv[2], gzv[3]);
    }
    __syncthreads();

    // centers for this thread's two quad slots
    float4 c0 = xyzp[pbase + ((ch * CHQ + tid) >> 2)];
    float4 c1 = xyzp[pbase + ((ch * CHQ + 256 + tid) >> 2)];

    const float4* fw4 = (const float4*)fw;
    float* ob = out + (size_t)b * 32 * LL + (size_t)ch * CHP;
#pragma unroll 4
    for (int oi = 0; oi < 32; ++oi) {
        int o = (oi + bid) & 31;                 // per-block slab rotation
        float4 wA = fw4[o * 2];                  // {A, U0, U1, U2}
        float4 wB = fw4[o * 2 + 1];              // {V0, V1, V2, Fb}
        float* oo = ob + (size_t)o * LL;
#pragma unroll
        for (int it2 = 0; it2 < 2; ++it2) {
            int q2 = it2 * 256 + tid;
            float4 c = it2 ? c1 : c0;
            float hc = wB.w + wA.y * c.x + wA.z * c.y + wA.w * c.z;
            float4 d4 = *(const float4*)&sdl[q2 * 4];
            float4 x4 = *(const float4*)&sgx[q2 * 4];
            float4 y4 = *(const float4*)&sgy[q2 * 4];
            float4 z4 = *(const float4*)&sgz[q2 * 4];
            float h0 = hc + wA.x * d4.x + wB.x * x4.x + wB.y * y4.x + wB.z * z4.x;
            float h1 = hc + wA.x * d4.y + wB.x * x4.y + wB.y * y4.y + wB.z * z4.y;
            float h2 = hc + wA.x * d4.z + wB.x * x4.z + wB.y * y4.z + wB.z * z4.z;
            float h3 = hc + wA.x * d4.w + wB.x * x4.w + wB.y * y4.w + wB.z * z4.w;
            nfloat4 r = {fmaxf(h0, 0.01f * h0), fmaxf(h1, 0.01f * h1),
                         fmaxf(h2, 0.01f * h2), fmaxf(h3, 0.01f * h3)};
            __builtin_nontemporal_store(r, (nfloat4*)(oo + q2 * 4));
        }
    }
}

extern "C" void kernel_launch(void* const* d_in, const int* in_sizes, int n_in,
                              void* d_out, int out_size, void* d_ws, size_t ws_size,
                              hipStream_t stream) {
    const float* xyz   = (const float*)d_in[0];
    const int*   nidx  = (const int*)d_in[1];
    const float* W     = (const float*)d_in[2];
    const float* bias  = (const float*)d_in[3];
    const float* gamma = (const float*)d_in[4];
    const float* beta  = (const float*)d_in[5];
    float*       out   = (float*)d_out;

    char* ws = (char*)d_ws;
    float4* xyzp    = (float4*)(ws + XYZP_OFF);
    float*  partial = (float*)(ws + PART_OFF);
    float*  fw      = (float*)(ws + FW_OFF);
    const int4* idx4 = (const int4*)nidx;

    k_transpose<<<NP / 256, 256, 0, stream>>>(xyz, xyzp);
    k_stats<<<NBLKS, 256, 0, stream>>>(xyzp, idx4, partial);
    k_finalize<<<1, dim3(35, 8), 0, stream>>>(partial, W, bias, gamma, beta, fw);
    k_apply_v2<<<BB * NCHB, 256, 0, stream>>>(xyzp, idx4, fw, out);
}